// Round 4
// baseline (15173.882 us; speedup 1.0000x reference)
//
#include <hip/hip_runtime.h>
#include <hip/hip_bf16.h>

#define B_    32
#define T_    2048
#define F_    512
#define H_    512
#define G_    64          // workgroups (one per 8 h-columns)
#define NCOL  32          // z-columns per WG (4 gates x 8 h-cols)
#define WPITCH 520        // LDS pitch (shorts) for transposed weight rows
#define BH    (B_ * H_)
#define DSL   4           // tagged-u32 h ring depth (4 x 64 KB); >=2 gives flow control

typedef __attribute__((ext_vector_type(8))) short short8;     // 8 x bf16
typedef __attribute__((ext_vector_type(4))) float floatx4;
typedef __attribute__((ext_vector_type(4))) unsigned int uint4v;

static __device__ __forceinline__ unsigned short bf16u(float f) {
    return (unsigned short)__builtin_bit_cast(short, __float2bfloat16(f));
}
__device__ __forceinline__ float sigmoidf_(float x) {
    return 1.0f / (1.0f + __expf(-x));
}

// Issue 2x16B agent-coherent loads (bypass L1+L2 -> MALL), no wait.
#define ISSUE2(w0_, w1_, p_)                                                 \
    asm volatile("global_load_dwordx4 %0, %2, off sc0 sc1\n\t"               \
                 "global_load_dwordx4 %1, %3, off sc0 sc1"                   \
                 : "=&v"(w0_), "=&v"(w1_)                                    \
                 : "v"(p_), "v"((p_) + 4) : "memory")
// Re-issue + full drain (rare retry path)
#define REISSUE2(w0_, w1_, p_)                                               \
    asm volatile("global_load_dwordx4 %0, %2, off sc0 sc1\n\t"               \
                 "global_load_dwordx4 %1, %3, off sc0 sc1\n\t"               \
                 "s_waitcnt vmcnt(0)"                                        \
                 : "=&v"(w0_), "=&v"(w1_)                                    \
                 : "v"(p_), "v"((p_) + 4) : "memory")
#define WAITV(n) asm volatile("s_waitcnt vmcnt(" #n ")" ::: "memory")

__device__ __forceinline__ bool tagok(uint4v a, uint4v b, unsigned tg) {
    unsigned m = ((a.x >> 16) ^ tg) | ((a.y >> 16) ^ tg) |
                 ((a.z >> 16) ^ tg) | ((a.w >> 16) ^ tg) |
                 ((b.x >> 16) ^ tg) | ((b.y >> 16) ^ tg) |
                 ((b.z >> 16) ^ tg) | ((b.w >> 16) ^ tg);
    return m == 0;
}
__device__ __forceinline__ short8 unpack8(uint4v a, uint4v b) {
    short8 r;
    r[0] = (short)a.x; r[1] = (short)a.y; r[2] = (short)a.z; r[3] = (short)a.w;
    r[4] = (short)b.x; r[5] = (short)b.y; r[6] = (short)b.z; r[7] = (short)b.w;
    return r;
}

// ---------------- prep: x fp32 -> bf16; h0 -> ring slot DSL-1 (tag 0xFFFF) ----------------
__global__ void prep_kernel(const float* __restrict__ x,
                            const float* __restrict__ h0,
                            unsigned short* __restrict__ xb,
                            unsigned int* __restrict__ ring,
                            int do_x)
{
    const int tid = threadIdx.x;
    if (blockIdx.x < 64) {
        const int idx = blockIdx.x * 256 + tid;          // 16384 == B*H
        const unsigned v = (0xFFFFu << 16) | (unsigned)bf16u(h0[idx]);
        __hip_atomic_store(&ring[(DSL - 1) * BH + idx], v,
                           __ATOMIC_RELAXED, __HIP_MEMORY_SCOPE_AGENT);
        return;
    }
    if (!do_x) return;
    const long long base = ((long long)(blockIdx.x - 64) * 256 + tid) * 8;
    const floatx4 a = *(const floatx4*)(x + base);
    const floatx4 b = *(const floatx4*)(x + base + 4);
    short8 s;
    s[0] = (short)bf16u(a[0]); s[1] = (short)bf16u(a[1]);
    s[2] = (short)bf16u(a[2]); s[3] = (short)bf16u(a[3]);
    s[4] = (short)bf16u(b[0]); s[5] = (short)bf16u(b[1]);
    s[6] = (short)bf16u(b[2]); s[7] = (short)bf16u(b[3]);
    *(short8*)(xb + base) = s;
}

// ---------------- persistent recurrent kernel ----------------
template<bool XB>
__global__ __launch_bounds__(256, 1)
void lstm_loop(const float* __restrict__ x,
               const unsigned short* __restrict__ xb,
               const float* __restrict__ c0,
               const float* __restrict__ Wi,
               const float* __restrict__ Wh,
               const float* __restrict__ bias,
               float* __restrict__ out,
               unsigned int* __restrict__ ring)     // [DSL][B*H] tagged u32 h ring
{
    __shared__ short wtI[NCOL][WPITCH];
    __shared__ short wtH[NCOL][WPITCH];
    __shared__ float zbuf[B_][NCOL + 1];

    const int tid = threadIdx.x;
    const int wg  = blockIdx.x;

    // one-time: transposed bf16 weight slices into LDS
    for (int idx = tid; idx < NCOL * F_; idx += 256) {
        const int j  = idx & (NCOL - 1);
        const int k  = idx >> 5;
        const int gi = j >> 3, hc = j & 7;
        const int gcol = gi * H_ + wg * 8 + hc;
        wtI[j][k] = (short)bf16u(Wi[k * (4 * H_) + gcol]);
        wtH[j][k] = (short)bf16u(Wh[k * (4 * H_) + gcol]);
    }

    // gate-thread state: one (batch, h) cell per thread
    const int gb    = tid >> 3;
    const int ghc   = tid & 7;
    const int hglob = wg * 8 + ghc;
    float c_val  = c0[gb * H_ + hglob];
    float h_last = 0.f;
    const float bi = bias[0 * H_ + hglob];
    const float bf = bias[1 * H_ + hglob];
    const float bg = bias[2 * H_ + hglob];
    const float bo = bias[3 * H_ + hglob];

    // wave / MFMA tile ids
    const int wid  = tid >> 6;
    const int lane = tid & 63;
    const int mt   = wid >> 1;           // batch tile
    const int nt   = wid & 1;            // col tile
    const int ln   = lane & 15;
    const int lq   = lane >> 4;
    const int arow = mt * 16 + ln;

    float* ys = out + 2 * B_ * H_;

    __syncthreads();   // LDS weights ready

    for (int t = 0; t < T_; ++t) {
        // ---- x-part GEMM (recurrence-independent; overlaps h(t-1) propagation) ----
        floatx4 accx = {0.f, 0.f, 0.f, 0.f};
        if (XB) {
            const unsigned short* xrow = xb + (arow * T_ + t) * F_;
            #pragma unroll
            for (int ks = 0; ks < 16; ++ks) {
                const int koff = ks * 32 + lq * 8;
                const short8 ax = *(const short8*)(xrow + koff);
                const short8 bx = *(const short8*)&wtI[nt * 16 + ln][koff];
                accx = __builtin_amdgcn_mfma_f32_16x16x32_bf16(ax, bx, accx, 0, 0, 0);
            }
        } else {
            const float* xrow = x + (arow * T_ + t) * F_;
            #pragma unroll
            for (int ks = 0; ks < 16; ++ks) {
                const int koff = ks * 32 + lq * 8;
                const floatx4 xa = *(const floatx4*)(xrow + koff);
                const floatx4 xc = *(const floatx4*)(xrow + koff + 4);
                short8 ax;
                ax[0] = (short)bf16u(xa[0]); ax[1] = (short)bf16u(xa[1]);
                ax[2] = (short)bf16u(xa[2]); ax[3] = (short)bf16u(xa[3]);
                ax[4] = (short)bf16u(xc[0]); ax[5] = (short)bf16u(xc[1]);
                ax[6] = (short)bf16u(xc[2]); ax[7] = (short)bf16u(xc[3]);
                const short8 bx = *(const short8*)&wtI[nt * 16 + ln][koff];
                accx = __builtin_amdgcn_mfma_f32_16x16x32_bf16(ax, bx, accx, 0, 0, 0);
            }
        }

        // ---- h-part: tag-checked sc1 loads ARE the poll (one MALL leg), pipelined ----
        const unsigned int* hslot = ring + ((t - 1) & (DSL - 1)) * BH + arow * H_ + lq * 8;
        const unsigned tg = (unsigned)((t - 1) & 0xFFFF);
        floatx4 acch = {0.f, 0.f, 0.f, 0.f};
        uint4v wa[4], wb[4];

        // prologue: window of 4 groups (8 dwordx4 in flight)
        #pragma unroll
        for (int g = 0; g < 4; ++g) { ISSUE2(wa[g], wb[g], hslot + g * 32); }

        #pragma unroll
        for (int ks = 0; ks < 16; ++ks) {
            // happy-path wait retires exactly group ks (2 oldest loads)
            if (ks <= 12)      { WAITV(6); }
            else if (ks == 13) { WAITV(4); }
            else if (ks == 14) { WAITV(2); }
            else               { WAITV(0); }

            const int slot4 = ks & 3;
            if (!tagok(wa[slot4], wb[slot4], tg)) {
                int spins = 0;
                do {
                    REISSUE2(wa[slot4], wb[slot4], hslot + ks * 32);
                } while (!tagok(wa[slot4], wb[slot4], tg) && ++spins < (1 << 13));
            }
            const short8 ah = unpack8(wa[slot4], wb[slot4]);
            if (ks + 4 < 16) { ISSUE2(wa[slot4], wb[slot4], hslot + (ks + 4) * 32); }

            const short8 bh = *(const short8*)&wtH[nt * 16 + ln][ks * 32 + lq * 8];
            acch = __builtin_amdgcn_mfma_f32_16x16x32_bf16(ah, bh, acch, 0, 0, 0);
        }

        // C/D layout: col = lane&15, row = (lane>>4)*4 + reg  [m89-verified]
        {
            const int zrow = mt * 16 + lq * 4;
            const int zcol = nt * 16 + ln;
            #pragma unroll
            for (int r = 0; r < 4; ++r)
                zbuf[zrow + r][zcol] = accx[r] + acch[r];
        }
        __syncthreads();

        // ---- gates + immediate tagged publish (fire-and-forget sc1 stores) ----
        {
            const float zi = zbuf[gb][ghc]       + bi;
            const float zf = zbuf[gb][8  + ghc]  + bf;
            const float zg = zbuf[gb][16 + ghc]  + bg;
            const float zo = zbuf[gb][24 + ghc]  + bo;
            const float ig = sigmoidf_(zi);
            const float fg = sigmoidf_(zf);
            const float gg = tanhf(zg);
            const float og = sigmoidf_(zo);
            c_val  = fg * c_val + ig * gg;
            h_last = og * tanhf(c_val);
            const unsigned v = ((unsigned)(t & 0xFFFF) << 16) | (unsigned)bf16u(h_last);
            __hip_atomic_store(&ring[(t & (DSL - 1)) * BH + gb * H_ + hglob], v,
                               __ATOMIC_RELAXED, __HIP_MEMORY_SCOPE_AGENT);
            ys[(gb * T_ + t) * H_ + hglob] = h_last;   // fp32 output
        }
        __syncthreads();   // zbuf WAR protection for next step
    }

    // finals: c_fin | h_fin (fp32)
    out[gb * H_ + hglob]           = c_val;
    out[B_ * H_ + gb * H_ + hglob] = h_last;
}

extern "C" void kernel_launch(void* const* d_in, const int* in_sizes, int n_in,
                              void* d_out, int out_size, void* d_ws, size_t ws_size,
                              hipStream_t stream) {
    const float* x  = (const float*)d_in[0];
    const float* c0 = (const float*)d_in[1];
    const float* h0 = (const float*)d_in[2];
    const float* Wi = (const float*)d_in[3];
    const float* Wh = (const float*)d_in[4];
    const float* b  = (const float*)d_in[5];
    float* out = (float*)d_out;

    unsigned char* ws = (unsigned char*)d_ws;
    unsigned int*   ring = (unsigned int*)ws;                        // DSL * 64 KB = 256 KB
    unsigned short* xb   = (unsigned short*)(ws + (size_t)DSL * BH * 4);

    const size_t need_xb = (size_t)DSL * BH * 4 + (size_t)B_ * T_ * F_ * 2;
    const int use_xb = (ws_size >= need_xb) ? 1 : 0;

    // ring poison tag 0xAAAA never collides with tags {0xFFFF, 0..2046}: no memset needed.
    const int prep_blocks = 64 + (use_xb ? (B_ * T_ * F_ / 8 / 256) : 0);
    prep_kernel<<<prep_blocks, 256, 0, stream>>>(x, h0, xb, ring, use_xb);

    void* args[] = { &x, &xb, &c0, &Wi, &Wh, &b, &out, &ring };
    hipLaunchCooperativeKernel(use_xb ? (void*)lstm_loop<true> : (void*)lstm_loop<false>,
                               dim3(G_), dim3(256), args, 0, stream);
}